// Round 9
// baseline (188.750 us; speedup 1.0000x reference)
//
#include <hip/hip_runtime.h>

// SEIR SDE: B=32768 x 1000 steps -> out[step][4][B] f32 = 524 MB (write-bound).
// Ladder: 242 -> 115.6 -> ~110 plateau -> 97.2 (R7 producer/consumer waves).
// R8 (no vmcnt drain at barriers) was neutral -> store wave is NOT critical;
// the COMPUTE wave is (233 cyc/step vs 183 cyc/step HBM-drain floor).
// R9 shrinks compute: (1) fold DT into rate constants and use
// sqrt(rate*DT)*w_raw == sqrt(rate)*sqrt(DT)*w (regrouping, ulp-level diff)
// -> kills 3 muls/step AND the noise pre-scaling; (2) noise read as uniform
// s_load_dwordx4 straight from dW (no LDS wbuf, no per-step ds_read);
// (3) per-step ~26 VALU + 4 ds_write ~= 90-110 cyc < drain. Store wave then
// becomes critical; R8's stores-in-flight-across-barrier structure is kept.

constexpr int   B_TRAJ  = 32768;
constexpr int   NSTEPS  = 1000;
constexpr int   K       = 20;            // steps per chunk
constexpr int   NC      = NSTEPS / K;    // 50 chunks
constexpr float DT      = 0.01f;
constexpr float EPS     = 1e-6f;
constexpr float INV_N   = 1.0f / 10000.0f;

// Barrier that does NOT drain vmcnt: LDS ordering only. Global stores stay
// in flight across chunk boundaries (counted-vmcnt via register rotation).
__device__ __forceinline__ void barrier_lds_only() {
    asm volatile("s_waitcnt lgkmcnt(0)" ::: "memory");
    __builtin_amdgcn_s_barrier();
    asm volatile("" ::: "memory");
}

__global__ __launch_bounds__(128) void seir_sde_kernel(
    const float* __restrict__ beta,
    const float* __restrict__ sigma,
    const float* __restrict__ gamma,
    const float* __restrict__ S0,
    const float* __restrict__ E0,
    const float* __restrict__ I0,
    const float* __restrict__ R0,
    const float4* __restrict__ dW,   // [NSTEPS] raw (w0,w1,w2,w3)
    float* __restrict__ out)         // [NSTEPS][4][B_TRAJ]
{
    __shared__ float ring[2][K][4][64];      // double-buffered chunk, 40 KB

    const int lane = threadIdx.x & 63;
    const int wid  = threadIdx.x >> 6;       // 0 = compute wave, 1 = store wave

    // Compute-wave state (dead in store wave). DT folded into rate constants:
    // iD = (beta/N*DT)*S*I, eD = (sigma*DT)*E, rD = (gamma*DT)*I, and the
    // diffusion uses sqrt(iD)*w_raw == sqrt(rate)*sqrt(DT)*w_raw.
    float S = 0.f, E = 0.f, I = 0.f, R = 0.f, btnD = 0.f, sgD = 0.f, gmD = 0.f;
    if (wid == 0) {
        const int b = blockIdx.x * 64 + lane;
        S = S0[b]; E = E0[b]; I = I0[b]; R = R0[b];
        btnD = beta[0] * INV_N * DT;
        sgD  = sigma[0] * DT;
        gmD  = gamma[0] * DT;
    }

    // Store-wave addressing: lane l -> component (l>>4), trajectories
    // 4*(l&15)..+3 of this block. One dwordx4 = 4 x 256B segments.
    float* const obase = out + blockIdx.x * 64
                             + (lane >> 4) * B_TRAJ + (lane & 15) * 4;

    // One SEIR step: noise w is wave-uniform (s_load path), raw (unscaled).
    #define SEIR_STEP(w, dst)                                                  \
    {                                                                          \
        const float Sc = fmaxf(S, EPS);                                        \
        const float Ec = fmaxf(E, EPS);                                        \
        const float Ic = fmaxf(I, EPS);                                        \
        const float Rc = fmaxf(R, EPS);                                        \
        const float iD = btnD * Sc * Ic;      /* inf_rate*DT */                \
        const float eD = sgD * Ec;            /* exp_rate*DT */                \
        const float rD = gmD * Ic;            /* rec_rate*DT */                \
        const float ai = __builtin_amdgcn_sqrtf(iD) * (w).x;                   \
        const float ae = __builtin_amdgcn_sqrtf(eD) * (w).y;                   \
        const float ar = __builtin_amdgcn_sqrtf(rD) * (w).z;                   \
        const float Sn = Sc - iD - ai;                                         \
        const float En = Ec + iD - eD + ai - ae;                               \
        const float In = Ic + eD - rD + ae - ar;                               \
        const float Rn = Rc + rD + ar;                                         \
        (dst)[0][lane] = Sn;                                                   \
        (dst)[1][lane] = En;                                                   \
        (dst)[2][lane] = In;                                                   \
        (dst)[3][lane] = Rn;                                                   \
        S = Sn; E = En; I = In; R = Rn;                                        \
    }

    // ---- prologue: compute wave fills chunk 0 into ring[0] ----
    if (wid == 0) {
        #pragma unroll
        for (int k = 0; k < K; ++k) {
            const float4 w = dW[k];          // uniform -> s_load_dwordx4 (K$)
            SEIR_STEP(w, ring[0][k]);
        }
    }
    barrier_lds_only();

    // ---- pipeline: iter c drains chunk c while filling chunk c+1 ----
    for (int c = 0; c < NC; ++c) {
        if (wid == 0) {
            if (c + 1 < NC) {
                const int s0 = (c + 1) * K;
                float (*rw)[4][64] = ring[(c + 1) & 1];
                #pragma unroll
                for (int k = 0; k < K; ++k) {
                    const float4 w = dW[s0 + k];
                    SEIR_STEP(w, rw[k]);
                }
            }
        } else {
            // Drain chunk c: K x { ds_read_b128 + global_store_dwordx4 }.
            // Stores pipeline across chunks (no vmcnt drain at barriers).
            const float4* rd = (const float4*)&ring[c & 1][0][0][0];
            float* o = obase + (size_t)(c * K) * (4 * B_TRAJ);
            #pragma unroll
            for (int k = 0; k < K; ++k) {
                const float4 v = rd[k * 64 + lane];   // contiguous 1KB/step
                *(float4*)o = v;
                o += 4 * B_TRAJ;
            }
        }
        barrier_lds_only();
    }
    #undef SEIR_STEP
}

extern "C" void kernel_launch(void* const* d_in, const int* in_sizes, int n_in,
                              void* d_out, int out_size, void* d_ws, size_t ws_size,
                              hipStream_t stream) {
    const float*  beta  = (const float*)d_in[0];
    const float*  sigma = (const float*)d_in[1];
    const float*  gamma = (const float*)d_in[2];
    const float*  S0    = (const float*)d_in[3];
    const float*  E0    = (const float*)d_in[4];
    const float*  I0    = (const float*)d_in[5];
    const float*  R0    = (const float*)d_in[6];
    const float4* dW    = (const float4*)d_in[7];
    float* out = (float*)d_out;

    seir_sde_kernel<<<B_TRAJ / 64, 128, 0, stream>>>(
        beta, sigma, gamma, S0, E0, I0, R0, dW, out);
}

// Round 10
// 120.155 us; speedup vs baseline: 1.5709x; 1.5709x over previous
//
#include <hip/hip_runtime.h>

// SEIR SDE: B=32768 x 1000 steps -> out[step][4][B] f32 = 524 MB (write-bound).
// Ladder: 242 -> 115.6 -> 97.2 (R7 producer/consumer) -> R8 neutral -> R9
// regression (SMEM noise: s_load shares lgkmcnt with ds ops, forced lgkmcnt(0)
// per step). Established: COMPUTE wave is critical (~233 cyc/step vs 183
// cyc/step HBM drain floor), dominated by dependent-chain stalls at ILP=1.
// R10: 2 trajectories per compute thread (ILP=2) -> stall bubbles filled by
// the second chain. Block = 1 compute wave (128 trajs) + 1 store wave,
// grid = 256. Noise stays in LDS (R9 lesson), DT-folded algebra kept (R9:
// absmax 0.0), stores stay in flight across raw lds-only barriers (R8).

constexpr int   B_TRAJ  = 32768;
constexpr int   NSTEPS  = 1000;
constexpr int   K       = 10;            // steps per chunk
constexpr int   NC      = NSTEPS / K;    // 100 chunks
constexpr int   TPB     = 128;           // trajectories per block
constexpr float DT      = 0.01f;
constexpr float EPS     = 1e-6f;
constexpr float INV_N   = 1.0f / 10000.0f;

// Barrier that does NOT drain vmcnt: LDS ordering only. Global stores stay
// in flight across chunk boundaries.
__device__ __forceinline__ void barrier_lds_only() {
    asm volatile("s_waitcnt lgkmcnt(0)" ::: "memory");
    __builtin_amdgcn_s_barrier();
    asm volatile("" ::: "memory");
}

__global__ __launch_bounds__(128) void seir_sde_kernel(
    const float* __restrict__ beta,
    const float* __restrict__ sigma,
    const float* __restrict__ gamma,
    const float* __restrict__ S0,
    const float* __restrict__ E0,
    const float* __restrict__ I0,
    const float* __restrict__ R0,
    const float4* __restrict__ dW,   // [NSTEPS] raw (w0,w1,w2,w3)
    float* __restrict__ out)         // [NSTEPS][4][B_TRAJ]
{
    __shared__ float4 wbuf[NSTEPS];          // raw noise, 16 KB (LDS, not SMEM!)
    __shared__ float  ring[2][K][4][TPB];    // double-buffered chunk, 40 KB

    for (int i = threadIdx.x; i < NSTEPS; i += 128)
        wbuf[i] = dW[i];                     // unscaled; sqrt(DT) folded below

    const int lane = threadIdx.x & 63;
    const int wid  = threadIdx.x >> 6;       // 0 = compute wave, 1 = store wave

    // Compute wave: lane owns trajectories base, base+1 (two independent chains).
    float Sa=0.f,Ea=0.f,Ia=0.f,Ra=0.f, Sb=0.f,Eb=0.f,Ib=0.f,Rb=0.f;
    float btnD=0.f, sgD=0.f, gmD=0.f;
    if (wid == 0) {
        const int base = blockIdx.x * TPB + 2 * lane;
        Sa = S0[base]; Ea = E0[base]; Ia = I0[base]; Ra = R0[base];
        Sb = S0[base+1]; Eb = E0[base+1]; Ib = I0[base+1]; Rb = R0[base+1];
        btnD = beta[0] * INV_N * DT;
        sgD  = sigma[0] * DT;
        gmD  = gamma[0] * DT;
    }

    // Store wave: per step 2KB = 128 float4. Load j=lane -> comp lane>>5 (0,1),
    // load j=64+lane -> comp 2+(lane>>5); traj quad (lane&31)*4. Each is a
    // 512B-contiguous row segment per 32 lanes.
    float* ob0 = out + blockIdx.x * TPB + (lane >> 5) * B_TRAJ + (lane & 31) * 4;
    float* ob1 = out + blockIdx.x * TPB + (2 + (lane >> 5)) * B_TRAJ + (lane & 31) * 4;

    // Two independent SEIR chains per thread; expressions verbatim from R9
    // (validated absmax 0.0). ds_writes packed as float2 (2-way bank alias = free).
    #define SEIR2(w, dstk)                                                     \
    {                                                                          \
        const float Sc0=fmaxf(Sa,EPS), Ec0=fmaxf(Ea,EPS);                      \
        const float Ic0=fmaxf(Ia,EPS), Rc0=fmaxf(Ra,EPS);                      \
        const float Sc1=fmaxf(Sb,EPS), Ec1=fmaxf(Eb,EPS);                      \
        const float Ic1=fmaxf(Ib,EPS), Rc1=fmaxf(Rb,EPS);                      \
        const float iD0=btnD*Sc0*Ic0, eD0=sgD*Ec0, rD0=gmD*Ic0;                \
        const float iD1=btnD*Sc1*Ic1, eD1=sgD*Ec1, rD1=gmD*Ic1;                \
        const float ai0=__builtin_amdgcn_sqrtf(iD0)*(w).x;                     \
        const float ae0=__builtin_amdgcn_sqrtf(eD0)*(w).y;                     \
        const float ar0=__builtin_amdgcn_sqrtf(rD0)*(w).z;                     \
        const float ai1=__builtin_amdgcn_sqrtf(iD1)*(w).x;                     \
        const float ae1=__builtin_amdgcn_sqrtf(eD1)*(w).y;                     \
        const float ar1=__builtin_amdgcn_sqrtf(rD1)*(w).z;                     \
        const float Sn0=Sc0-iD0-ai0,  En0=Ec0+iD0-eD0+ai0-ae0;                 \
        const float In0=Ic0+eD0-rD0+ae0-ar0, Rn0=Rc0+rD0+ar0;                  \
        const float Sn1=Sc1-iD1-ai1,  En1=Ec1+iD1-eD1+ai1-ae1;                 \
        const float In1=Ic1+eD1-rD1+ae1-ar1, Rn1=Rc1+rD1+ar1;                  \
        *(float2*)&(dstk)[0][2*lane] = make_float2(Sn0, Sn1);                  \
        *(float2*)&(dstk)[1][2*lane] = make_float2(En0, En1);                  \
        *(float2*)&(dstk)[2][2*lane] = make_float2(In0, In1);                  \
        *(float2*)&(dstk)[3][2*lane] = make_float2(Rn0, Rn1);                  \
        Sa=Sn0; Ea=En0; Ia=In0; Ra=Rn0;                                        \
        Sb=Sn1; Eb=En1; Ib=In1; Rb=Rn1;                                        \
    }

    __syncthreads();                         // noise staged (once; full drain ok)

    // ---- prologue: compute wave fills chunk 0 ----
    if (wid == 0) {
        #pragma unroll
        for (int k = 0; k < K; ++k) {
            const float4 w = wbuf[k];        // uniform LDS broadcast
            SEIR2(w, ring[0][k]);
        }
    }
    barrier_lds_only();

    // ---- pipeline: iter c drains chunk c while filling chunk c+1 ----
    for (int c = 0; c < NC; ++c) {
        if (wid == 0) {
            if (c + 1 < NC) {
                const int s0 = (c + 1) * K;
                float (*rw)[4][TPB] = ring[(c + 1) & 1];
                #pragma unroll
                for (int k = 0; k < K; ++k) {
                    const float4 w = wbuf[s0 + k];
                    SEIR2(w, rw[k]);
                }
            }
        } else {
            // Drain chunk c: per step 2 ds_read_b128 + 2 global_store_dwordx4.
            const float4* rd = (const float4*)&ring[c & 1][0][0][0];
            float* o0 = ob0 + (size_t)(c * K) * (4 * B_TRAJ);
            float* o1 = ob1 + (size_t)(c * K) * (4 * B_TRAJ);
            #pragma unroll
            for (int k = 0; k < K; ++k) {
                const float4 v0 = rd[k * (TPB/4 * 4) + lane];        // j = lane
                const float4 v1 = rd[k * (TPB/4 * 4) + 64 + lane];   // j = 64+lane
                *(float4*)o0 = v0;
                *(float4*)o1 = v1;
                o0 += 4 * B_TRAJ;
                o1 += 4 * B_TRAJ;
            }
        }
        barrier_lds_only();
    }
    #undef SEIR2
}

extern "C" void kernel_launch(void* const* d_in, const int* in_sizes, int n_in,
                              void* d_out, int out_size, void* d_ws, size_t ws_size,
                              hipStream_t stream) {
    const float*  beta  = (const float*)d_in[0];
    const float*  sigma = (const float*)d_in[1];
    const float*  gamma = (const float*)d_in[2];
    const float*  S0    = (const float*)d_in[3];
    const float*  E0    = (const float*)d_in[4];
    const float*  I0    = (const float*)d_in[5];
    const float*  R0    = (const float*)d_in[6];
    const float4* dW    = (const float4*)d_in[7];
    float* out = (float*)d_out;

    seir_sde_kernel<<<B_TRAJ / TPB, 128, 0, stream>>>(
        beta, sigma, gamma, S0, E0, I0, R0, dW, out);
}

// Round 11
// 102.930 us; speedup vs baseline: 1.8338x; 1.1673x over previous
//
#include <hip/hip_runtime.h>

// SEIR SDE: B=32768 x 1000 steps -> out[step][4][B] f32 = 524 MB (write-bound).
// Ladder: 242 -> 115.6 -> 97.2 (R7 producer/consumer waves; R8 neutral;
// R9 SMEM-noise regression; R10 ILP-on-one-SIMD regression -> reverted).
// Model: compute wave critical at 233 cyc/step; pure-VALU issue ~78 cyc and
// carried chain ~54 cyc don't explain it -> suspect per-step LDS ops
// (ds_read noise + 4 scattered ds_write_b32) and their lgkmcnt scheduling.
// R11: compute steps are LDS-free except ONE ds_write_b128:
//   - noise batched into registers per chunk (20 broadcast ds_reads, one
//     latency exposure per chunk),
//   - ring is AoS [K][64][4] so a lane writes its 4 comps as one b128,
//   - store wave does the transpose on the GLOBAL side: contiguous b128 LDS
//     read + 4x global_store_dword (each 256B coalesced). Zero bank conflicts.
// Topology R7 (512 blocks x {1 compute, 1 store} wave), R8 lds-only barriers,
// R9 DT-folded algebra (validated absmax 0.0).

constexpr int   B_TRAJ  = 32768;
constexpr int   NSTEPS  = 1000;
constexpr int   K       = 20;            // steps per chunk
constexpr int   NC      = NSTEPS / K;    // 50 chunks
constexpr float DT      = 0.01f;
constexpr float EPS     = 1e-6f;
constexpr float INV_N   = 1.0f / 10000.0f;

// Barrier without vmcnt drain: LDS ordering only; global stores stay in
// flight across chunk boundaries.
__device__ __forceinline__ void barrier_lds_only() {
    asm volatile("s_waitcnt lgkmcnt(0)" ::: "memory");
    __builtin_amdgcn_s_barrier();
    asm volatile("" ::: "memory");
}

__global__ __launch_bounds__(128) void seir_sde_kernel(
    const float* __restrict__ beta,
    const float* __restrict__ sigma,
    const float* __restrict__ gamma,
    const float* __restrict__ S0,
    const float* __restrict__ E0,
    const float* __restrict__ I0,
    const float* __restrict__ R0,
    const float4* __restrict__ dW,   // [NSTEPS] raw (w0,w1,w2,w3)
    float* __restrict__ out)         // [NSTEPS][4][B_TRAJ]
{
    __shared__ float4 wbuf[NSTEPS];          // raw noise, 16 KB
    __shared__ float  ring[2][K][64][4];     // AoS chunk ring, 40 KB

    for (int i = threadIdx.x; i < NSTEPS; i += 128)
        wbuf[i] = dW[i];                     // unscaled; sqrt(DT) folded below

    const int lane = threadIdx.x & 63;
    const int wid  = threadIdx.x >> 6;       // 0 = compute wave, 1 = store wave

    float S=0.f, E=0.f, I=0.f, R=0.f, btnD=0.f, sgD=0.f, gmD=0.f;
    if (wid == 0) {
        const int b = blockIdx.x * 64 + lane;
        S = S0[b]; E = E0[b]; I = I0[b]; R = R0[b];
        btnD = beta[0] * INV_N * DT;         // (beta/N)*DT
        sgD  = sigma[0] * DT;                // sigma*DT
        gmD  = gamma[0] * DT;                // gamma*DT
    }

    // One SEIR step, pure VALU + one ds_write_b128. sqrt(rate*DT)*w_raw ==
    // sqrt(rate)*sqrt(DT)*w (regrouping; R9 validated absmax 0.0).
    #define SEIR_STEP(w, dstp)                                                 \
    {                                                                          \
        const float Sc = fmaxf(S, EPS);                                        \
        const float Ec = fmaxf(E, EPS);                                        \
        const float Ic = fmaxf(I, EPS);                                        \
        const float Rc = fmaxf(R, EPS);                                        \
        const float iD = btnD * Sc * Ic;                                       \
        const float eD = sgD * Ec;                                             \
        const float rD = gmD * Ic;                                             \
        const float ai = __builtin_amdgcn_sqrtf(iD) * (w).x;                   \
        const float ae = __builtin_amdgcn_sqrtf(eD) * (w).y;                   \
        const float ar = __builtin_amdgcn_sqrtf(rD) * (w).z;                   \
        const float Sn = Sc - iD - ai;                                         \
        const float En = Ec + iD - eD + ai - ae;                               \
        const float In = Ic + eD - rD + ae - ar;                               \
        const float Rn = Rc + rD + ar;                                         \
        *(float4*)(dstp) = make_float4(Sn, En, In, Rn);                        \
        S = Sn; E = En; I = In; R = Rn;                                        \
    }

    __syncthreads();                         // noise staged (once; full drain ok)

    // ---- prologue: compute wave fills chunk 0 ----
    if (wid == 0) {
        float4 wv[K];
        #pragma unroll
        for (int k = 0; k < K; ++k) wv[k] = wbuf[k];   // broadcast reads
        #pragma unroll
        for (int k = 0; k < K; ++k) SEIR_STEP(wv[k], &ring[0][k][lane][0]);
    }
    barrier_lds_only();

    // ---- pipeline: iter c drains chunk c while filling chunk c+1 ----
    for (int c = 0; c < NC; ++c) {
        if (wid == 0) {
            if (c + 1 < NC) {
                // Batch the chunk's noise into registers: one latency
                // exposure per chunk, zero per-step LDS reads.
                float4 wv[K];
                const int s0 = (c + 1) * K;
                #pragma unroll
                for (int k = 0; k < K; ++k) wv[k] = wbuf[s0 + k];
                float (*rw)[64][4] = ring[(c + 1) & 1];
                #pragma unroll
                for (int k = 0; k < K; ++k) SEIR_STEP(wv[k], &rw[k][lane][0]);
            }
        } else {
            // Drain chunk c: contiguous b128 LDS read (traj 'lane' x 4 comps)
            // + 4 coalesced global_store_dword (256B/wave each). Transpose is
            // free on the global side. Stores stay in flight across barriers.
            const float4* rd = (const float4*)&ring[c & 1][0][0][0];
            float* o = out + (size_t)(c * K) * (4 * B_TRAJ)
                           + blockIdx.x * 64 + lane;
            #pragma unroll
            for (int k = 0; k < K; ++k) {
                const float4 v = rd[k * 64 + lane];
                o[0 * B_TRAJ] = v.x;
                o[1 * B_TRAJ] = v.y;
                o[2 * B_TRAJ] = v.z;
                o[3 * B_TRAJ] = v.w;
                o += 4 * B_TRAJ;
            }
        }
        barrier_lds_only();
    }
    #undef SEIR_STEP
}

extern "C" void kernel_launch(void* const* d_in, const int* in_sizes, int n_in,
                              void* d_out, int out_size, void* d_ws, size_t ws_size,
                              hipStream_t stream) {
    const float*  beta  = (const float*)d_in[0];
    const float*  sigma = (const float*)d_in[1];
    const float*  gamma = (const float*)d_in[2];
    const float*  S0    = (const float*)d_in[3];
    const float*  E0    = (const float*)d_in[4];
    const float*  I0    = (const float*)d_in[5];
    const float*  R0    = (const float*)d_in[6];
    const float4* dW    = (const float4*)d_in[7];
    float* out = (float*)d_out;

    seir_sde_kernel<<<B_TRAJ / 64, 128, 0, stream>>>(
        beta, sigma, gamma, S0, E0, I0, R0, dW, out);
}

// Round 12
// 94.173 us; speedup vs baseline: 2.0043x; 1.0930x over previous
//
#include <hip/hip_runtime.h>

// SEIR SDE: B=32768 x 1000 steps -> out[step][4][B] f32 = 524 MB (write-bound).
// Ladder: 242 -> 115.6 -> 97.2 (R7 producer/consumer). R8 (no barrier drain),
// R11 (LDS-free compute) both neutral -> neither barrier nor compute-LDS is
// the limit. Little's law: need ~22KB/CU of stores continuously in flight;
// R7's store loop recycles few float4 regs -> compiler emits small-N vmcnt
// reuse waits -> ~8KB in flight, bursty, ~1000 cyc/chunk drain idle (= the
// observed 50 cyc/step gap over the 183 cyc/step HBM floor).
// R12: counted-vmcnt store pipeline in pure C++ — TWO register sets va/vb on
// manually-2-chunk-unrolled loop; chunk c's ds_reads overwrite set from chunk
// c-2, so WAR wait = vmcnt(~20): 20KB/wave (40KB/CU) in flight permanently.
// Also: noise pre-scaled to (sqrt(btnD)w, sqrt(sgD)w, sqrt(gmD)w) at staging
// -> per-step diffusion = sqrt(P)*w (shorter chain; regrouping, huge margin).

constexpr int   B_TRAJ  = 32768;
constexpr int   NSTEPS  = 1000;
constexpr int   K       = 20;            // steps per chunk
constexpr int   NC      = NSTEPS / K;    // 50 chunks (even)
constexpr float DT      = 0.01f;
constexpr float EPS     = 1e-6f;
constexpr float INV_N   = 1.0f / 10000.0f;

// Barrier without vmcnt drain: LDS ordering only; global stores stay in
// flight across chunk boundaries.
__device__ __forceinline__ void barrier_lds_only() {
    asm volatile("s_waitcnt lgkmcnt(0)" ::: "memory");
    __builtin_amdgcn_s_barrier();
    asm volatile("" ::: "memory");
}

__global__ __launch_bounds__(128) void seir_sde_kernel(
    const float* __restrict__ beta,
    const float* __restrict__ sigma,
    const float* __restrict__ gamma,
    const float* __restrict__ S0,
    const float* __restrict__ E0,
    const float* __restrict__ I0,
    const float* __restrict__ R0,
    const float4* __restrict__ dW,   // [NSTEPS] raw (w0,w1,w2,w3)
    float* __restrict__ out)         // [NSTEPS][4][B_TRAJ]
{
    __shared__ float4 wbuf[NSTEPS];          // pre-scaled noise, 16 KB
    __shared__ float  ring[2][K][4][64];     // SoA chunk ring, 40 KB

    // All threads compute the folded constants (3 scalar loads, once).
    const float btnD = beta[0] * INV_N * DT; // (beta/N)*DT
    const float sgD  = sigma[0] * DT;        // sigma*DT
    const float gmD  = gamma[0] * DT;        // gamma*DT
    const float sbi  = __builtin_amdgcn_sqrtf(btnD);
    const float sbe  = __builtin_amdgcn_sqrtf(sgD);
    const float sbr  = __builtin_amdgcn_sqrtf(gmD);

    // Stage noise pre-multiplied: per-step diffusion becomes sqrt(P)*w.
    for (int i = threadIdx.x; i < NSTEPS; i += 128) {
        const float4 w = dW[i];
        wbuf[i] = make_float4(w.x * sbi, w.y * sbe, w.z * sbr, 0.0f);
    }

    const int lane = threadIdx.x & 63;
    const int wid  = threadIdx.x >> 6;       // 0 = compute wave, 1 = store wave

    float S=0.f, E=0.f, I=0.f, R=0.f;
    if (wid == 0) {
        const int b = blockIdx.x * 64 + lane;
        S = S0[b]; E = E0[b]; I = I0[b]; R = R0[b];
    }

    // Store-wave addressing: lane l -> component (l>>4), trajectories
    // 4*(l&15)..+3 of this block. One dwordx4 = 4 x 256B segments.
    float* const obase = out + blockIdx.x * 64
                             + (lane >> 4) * B_TRAJ + (lane & 15) * 4;

    // One SEIR step. sqrt(rate*DT)*w_raw == sqrt(P)*(sqrt(const)*w_raw) with
    // the uniform factor folded into wbuf at staging (validated regrouping).
    #define SEIR_STEP(w, dst)                                                  \
    {                                                                          \
        const float Sc = fmaxf(S, EPS);                                        \
        const float Ec = fmaxf(E, EPS);                                        \
        const float Ic = fmaxf(I, EPS);                                        \
        const float Rc = fmaxf(R, EPS);                                        \
        const float P  = Sc * Ic;                                              \
        const float iD = btnD * P;                                             \
        const float eD = sgD * Ec;                                             \
        const float rD = gmD * Ic;                                             \
        const float ai = __builtin_amdgcn_sqrtf(P)  * (w).x;                   \
        const float ae = __builtin_amdgcn_sqrtf(Ec) * (w).y;                   \
        const float ar = __builtin_amdgcn_sqrtf(Ic) * (w).z;                   \
        const float Sn = Sc - iD - ai;                                         \
        const float En = Ec + iD - eD + ai - ae;                               \
        const float In = Ic + eD - rD + ae - ar;                               \
        const float Rn = Rc + rD + ar;                                         \
        (dst)[0][lane] = Sn;                                                   \
        (dst)[1][lane] = En;                                                   \
        (dst)[2][lane] = In;                                                   \
        (dst)[3][lane] = Rn;                                                   \
        S = Sn; E = En; I = In; R = Rn;                                        \
    }

    // Compute wave: fill chunk c into ring[c&1].
    #define FILL(c)                                                            \
    {                                                                          \
        const int s0 = (c) * K;                                                \
        float (*rw)[4][64] = ring[(c) & 1];                                    \
        _Pragma("unroll")                                                      \
        for (int k = 0; k < K; ++k) {                                          \
            const float4 w = wbuf[s0 + k];                                     \
            SEIR_STEP(w, rw[k]);                                               \
        }                                                                      \
    }

    // Store wave: drain chunk c through register set v (20 b128 reads, then
    // 20 dwordx4 stores). Alternating v sets across chunks => compiler's WAR
    // wait is vmcnt(~K), keeping a full chunk of stores in flight always.
    #define STORE_CHUNK(c, v)                                                  \
    {                                                                          \
        const float4* rd = (const float4*)&ring[(c) & 1][0][0][0];             \
        float* o = obase + (size_t)((c) * K) * (4 * B_TRAJ);                   \
        _Pragma("unroll")                                                      \
        for (int k = 0; k < K; ++k) v[k] = rd[k * 64 + lane];                  \
        _Pragma("unroll")                                                      \
        for (int k = 0; k < K; ++k) {                                          \
            *(float4*)o = v[k];                                                \
            o += 4 * B_TRAJ;                                                   \
        }                                                                      \
    }

    float4 va[K], vb[K];                     // two in-flight store sets

    __syncthreads();                         // noise staged (once; drain ok)

    // ---- prologue: compute wave fills chunk 0 ----
    if (wid == 0) FILL(0);
    barrier_lds_only();

    // ---- pipeline, 2 chunks per iteration (NC even) ----
    for (int cc = 0; cc < NC; cc += 2) {
        if (wid == 0) { FILL(cc + 1); }
        else          { STORE_CHUNK(cc, va); }
        barrier_lds_only();
        if (wid == 0) { if (cc + 2 < NC) FILL(cc + 2); }
        else          { STORE_CHUNK(cc + 1, vb); }
        barrier_lds_only();
    }
    #undef SEIR_STEP
    #undef FILL
    #undef STORE_CHUNK
}

extern "C" void kernel_launch(void* const* d_in, const int* in_sizes, int n_in,
                              void* d_out, int out_size, void* d_ws, size_t ws_size,
                              hipStream_t stream) {
    const float*  beta  = (const float*)d_in[0];
    const float*  sigma = (const float*)d_in[1];
    const float*  gamma = (const float*)d_in[2];
    const float*  S0    = (const float*)d_in[3];
    const float*  E0    = (const float*)d_in[4];
    const float*  I0    = (const float*)d_in[5];
    const float*  R0    = (const float*)d_in[6];
    const float4* dW    = (const float4*)d_in[7];
    float* out = (float*)d_out;

    seir_sde_kernel<<<B_TRAJ / 64, 128, 0, stream>>>(
        beta, sigma, gamma, S0, E0, I0, R0, dW, out);
}